// Round 11
// baseline (721.564 us; speedup 1.0000x reference)
//
#include <hip/hip_runtime.h>

#define B_ 512
#define T_ 1024
#define F_ 32
#define H0_ 64
#define H1_ 32
#define ROWS 2          // batch rows per block
#define NT 512          // 8 waves: 0-3 L0, 4-5 L1, 6-7 staging
#define CH 64           // x chunk (timesteps)
#define NCH (T_ / CH)

typedef _Float16 f16x8 __attribute__((ext_vector_type(8)));
typedef _Float16 f16x4 __attribute__((ext_vector_type(4)));
typedef float f32x4 __attribute__((ext_vector_type(4)));

__device__ __forceinline__ float exp2_f(float x) { return __builtin_amdgcn_exp2f(x); }
__device__ __forceinline__ float rcp_f(float x) { return __builtin_amdgcn_rcpf(x); }

__device__ __forceinline__ f16x8 cvt8(const float* p) {
    float4 a = *(const float4*)p;
    float4 b = *(const float4*)(p + 4);
    f16x8 o;
    o[0] = (_Float16)a.x; o[1] = (_Float16)a.y; o[2] = (_Float16)a.z; o[3] = (_Float16)a.w;
    o[4] = (_Float16)b.x; o[5] = (_Float16)b.y; o[6] = (_Float16)b.z; o[7] = (_Float16)b.w;
    return o;
}
__device__ __forceinline__ f16x4 cvt4(float4 v) {
    f16x4 o;
    o[0] = (_Float16)v.x; o[1] = (_Float16)v.y; o[2] = (_Float16)v.z; o[3] = (_Float16)v.w;
    return o;
}

#define K_SIG (-1.4426950408889634f)   /* sigmoid: 1/(1+2^(k*x)) */
#define K_TNH (-2.8853900817779268f)   /* tanh = 2/(1+2^(k*x)) - 1 */

__global__ void __launch_bounds__(NT, 1) lstm2_mfma_kernel(
    const float* __restrict__ x,
    const float* __restrict__ Wih0, const float* __restrict__ Whh0,
    const float* __restrict__ bih0, const float* __restrict__ bhh0,
    const float* __restrict__ Wih1, const float* __restrict__ Whh1,
    const float* __restrict__ bih1, const float* __restrict__ bhh1,
    const float* __restrict__ fcw, const float* __restrict__ fcb,
    float* __restrict__ out)
{
    // x chunk staged f16, [step][row][feat]
    __shared__ __align__(16) _Float16 xch[2][CH][ROWS][F_];   // 16 KB
    // recurrent state, double buffered, [row][unit]
    __shared__ __align__(16) _Float16 h0b[2][ROWS][H0_];      // 512 B
    __shared__ __align__(16) _Float16 h1b[2][ROWS][H1_];      // 256 B
    __shared__ float h1fin[ROWS][H1_];

    const int tid = threadIdx.x, blk = blockIdx.x;
    const int wv = tid >> 6, lane = tid & 63;
    const int lrow = lane & 15;      // frag M/N index
    const int lk   = lane >> 4;      // k-octet selector
    const bool isL0 = (wv < 4);
    const bool isL1 = (wv == 4 || wv == 5);
    const int U0 = isL0 ? 16 * wv : 16 * (wv - 4);   // unit-group base

    // ---------------- preload W as frags (used as MFMA *B* operand) ----------------
    // frag elem j = W[16t + lrow][8*lk + j]  (K-contiguous) — same load as round 8
    f16x8 aw[4][3];
    if (isL0) {
#pragma unroll
        for (int G = 0; G < 4; ++G) {
            const int r = G * H0_ + U0 + lrow;
            aw[G][0] = cvt8(&Wih0[r * F_ + 8 * lk]);          // k 0..31  (x)
            aw[G][1] = cvt8(&Whh0[r * H0_ + 8 * lk]);         // k 32..63 (h0 lo)
            aw[G][2] = cvt8(&Whh0[r * H0_ + 32 + 8 * lk]);    // k 64..95 (h0 hi)
        }
    } else if (isL1) {
#pragma unroll
        for (int G = 0; G < 4; ++G) {
            const int r = G * H1_ + U0 + lrow;
            aw[G][0] = cvt8(&Wih1[r * H0_ + 8 * lk]);         // k 0..31  (h0 lo)
            aw[G][1] = cvt8(&Wih1[r * H0_ + 32 + 8 * lk]);    // k 32..63 (h0 hi)
            aw[G][2] = cvt8(&Whh1[r * H1_ + 8 * lk]);         // k 64..95 (h1)
        }
    }

    // per-lane biases, premultiplied by activation constant (unit U0+lrow, gate G)
    float bK[4] = {0.f, 0.f, 0.f, 0.f};
    if (isL0) {
#pragma unroll
        for (int G = 0; G < 4; ++G) {
            const int r = G * H0_ + U0 + lrow;
            bK[G] = (bih0[r] + bhh0[r]) * ((G == 2) ? K_TNH : K_SIG);
        }
    } else if (isL1) {
#pragma unroll
        for (int G = 0; G < 4; ++G) {
            const int r = G * H1_ + U0 + lrow;
            bK[G] = (bih1[r] + bhh1[r]) * ((G == 2) ? K_TNH : K_SIG);
        }
    }

    // ---------------- stage chunk 0 + zero state ----------------
    {
        const float4* x4 = (const float4*)x;
#pragma unroll
        for (int k = 0; k < 2; ++k) {
            const int i = tid + k * NT;                 // 0..1023
            const int b = i >> 9, rem = i & 511;
            const int s2 = rem >> 3, f4 = rem & 7;
            float4 v = x4[(size_t)(2 * blk + b) * (T_ * (F_ / 4)) + s2 * (F_ / 4) + f4];
            *(f16x4*)&xch[0][s2][b][f4 * 4] = cvt4(v);
        }
    }
    if (tid < 256) ((_Float16*)h0b)[tid] = (_Float16)0.0f;
    if (tid < 128) ((_Float16*)h1b)[tid] = (_Float16)0.0f;
    __syncthreads();

    // ---------------- main recurrence: 1025 iterations ----------------
    // iter it: L0 computes h0[it] (it<1024); L1 computes h1[it-1] (it>=1). One barrier/iter.
    int p = 0, cb = 0;
    float cc[2] = {0.f, 0.f};    // cell state, batch 0/1
    float hh[2] = {0.f, 0.f};
    for (int it = 0; it <= T_; ++it) {
        const int s = it & (CH - 1);
        const bool active = (isL0 && it < T_) || (isL1 && it >= 1);
        if (active) {
            // z-frags (used as MFMA *A* operand): A row = lrow, batch = lrow&1 (rows 2..15
            // duplicate real batch data -> D rows 2..15 are valid-but-unused, no NaN risk)
            f16x8 b0, b1, b2;
            if (isL0) {
                b0 = *(const f16x8*)&xch[cb][s][lane & 1][8 * lk];
                b1 = *(const f16x8*)&h0b[p][lane & 1][8 * lk];
                b2 = *(const f16x8*)&h0b[p][lane & 1][32 + 8 * lk];
            } else {
                b0 = *(const f16x8*)&h0b[p][lane & 1][8 * lk];
                b1 = *(const f16x8*)&h0b[p][lane & 1][32 + 8 * lk];
                b2 = *(const f16x8*)&h1b[p][lane & 1][8 * lk];
            }
            // SWAPPED operands: D = z · W^T -> D[row=batch][col=unit].
            // acc[G][r] = gate G, unit U0+lrow, batch r  (r=0,1 valid; identical in every lk group)
            f32x4 acc[4];
#pragma unroll
            for (int G = 0; G < 4; ++G) {
                f32x4 a = {0.f, 0.f, 0.f, 0.f};
                a = __builtin_amdgcn_mfma_f32_16x16x32_f16(b0, aw[G][0], a, 0, 0, 0);
                a = __builtin_amdgcn_mfma_f32_16x16x32_f16(b1, aw[G][1], a, 0, 0, 0);
                a = __builtin_amdgcn_mfma_f32_16x16x32_f16(b2, aw[G][2], a, 0, 0, 0);
                acc[G] = a;
            }
            // fully lane-local cell update, both batches; each value computed once per lane
#pragma unroll
            for (int r = 0; r < 2; ++r) {
                const float gi = rcp_f(1.0f + exp2_f(fmaf(acc[0][r], K_SIG, bK[0])));
                const float gf = rcp_f(1.0f + exp2_f(fmaf(acc[1][r], K_SIG, bK[1])));
                const float gg = fmaf(2.0f, rcp_f(1.0f + exp2_f(fmaf(acc[2][r], K_TNH, bK[2]))), -1.0f);
                const float go = rcp_f(1.0f + exp2_f(fmaf(acc[3][r], K_SIG, bK[3])));
                cc[r] = fmaf(gf, cc[r], gi * gg);
                const float th = fmaf(2.0f, rcp_f(1.0f + exp2_f(cc[r] * K_TNH)), -1.0f);
                hh[r] = go * th;
            }
            if (lane < 16) {   // one writer per unit (lk==0 group)
                if (isL0) {
                    h0b[p ^ 1][0][U0 + lane] = (_Float16)hh[0];
                    h0b[p ^ 1][1][U0 + lane] = (_Float16)hh[1];
                } else {
                    h1b[p ^ 1][0][U0 + lane] = (_Float16)hh[0];
                    h1b[p ^ 1][1][U0 + lane] = (_Float16)hh[1];
                }
            }
        }
        if (wv >= 6) {
            // stage next x chunk during first iteration of each chunk
            if (s == 0 && (it >> 6) < (NCH - 1)) {
                const int tbase = it + CH;
                const float4* x4 = (const float4*)x;
                const int ls = tid - 384;               // 0..127
#pragma unroll
                for (int k = 0; k < 8; ++k) {
                    const int i = ls + k * 128;         // 0..1023
                    const int b = i >> 9, rem = i & 511;
                    const int s2 = rem >> 3, f4 = rem & 7;
                    float4 v = x4[(size_t)(2 * blk + b) * (T_ * (F_ / 4)) + (tbase + s2) * (F_ / 4) + f4];
                    *(f16x4*)&xch[cb ^ 1][s2][b][f4 * 4] = cvt4(v);
                }
            }
        }
        __syncthreads();
        p ^= 1;
        if (s == CH - 1) cb ^= 1;
    }

    // ---------------- epilogue ----------------
    float* hT0 = out + B_;
    float* cT0 = hT0 + B_ * H0_;
    float* hT1 = cT0 + B_ * H0_;
    float* cT1 = hT1 + B_ * H1_;
    if (lane < 16) {
        const int unit = U0 + lane;
        if (isL0) {
#pragma unroll
            for (int b = 0; b < 2; ++b) {
                hT0[(2 * blk + b) * H0_ + unit] = hh[b];
                cT0[(2 * blk + b) * H0_ + unit] = cc[b];
            }
        } else if (isL1) {
#pragma unroll
            for (int b = 0; b < 2; ++b) {
                hT1[(2 * blk + b) * H1_ + unit] = hh[b];
                cT1[(2 * blk + b) * H1_ + unit] = cc[b];
                h1fin[b][unit] = hh[b];
            }
        }
    }
    __syncthreads();
    if (wv == 0) {
        const int u = lane & 31, r = lane >> 5;
        float v = h1fin[r][u] * fcw[u];
        v += __shfl_xor(v, 16, 64);
        v += __shfl_xor(v, 8, 64);
        v += __shfl_xor(v, 4, 64);
        v += __shfl_xor(v, 2, 64);
        v += __shfl_xor(v, 1, 64);
        if (u == 0) out[2 * blk + r] = v + fcb[0];
    }
}

extern "C" void kernel_launch(void* const* d_in, const int* in_sizes, int n_in,
                              void* d_out, int out_size, void* d_ws, size_t ws_size,
                              hipStream_t stream) {
    const float* x    = (const float*)d_in[0];
    const float* Wih0 = (const float*)d_in[1];
    const float* Whh0 = (const float*)d_in[2];
    const float* bih0 = (const float*)d_in[3];
    const float* bhh0 = (const float*)d_in[4];
    const float* Wih1 = (const float*)d_in[5];
    const float* Whh1 = (const float*)d_in[6];
    const float* bih1 = (const float*)d_in[7];
    const float* bhh1 = (const float*)d_in[8];
    const float* fcw  = (const float*)d_in[9];
    const float* fcb  = (const float*)d_in[10];

    hipLaunchKernelGGL(lstm2_mfma_kernel, dim3(B_ / ROWS), dim3(NT), 0, stream,
                       x, Wih0, Whh0, bih0, bhh0, Wih1, Whh1, bih1, bhh1,
                       fcw, fcb, (float*)d_out);
}